// Round 8
// baseline (311.424 us; speedup 1.0000x reference)
//
#include <hip/hip_runtime.h>
#include <hip/hip_bf16.h>
#include <stdint.h>
#include <algorithm>

// VQ-VAE quantise round. N=16, W=512, T=1024, K=2048, NT=16384.
// Round 15: R14 base. One delta: argmin EPILOGUE merge parallelized 128->256
// threads (two 16-slot halves + LDS combine; packed-u64 total order -> merge
// order immaterial -> bit-identical). K-loop staging/swizzle/barriers FROZEN.

#define W_   512
#define T_   1024
#define K_   2048
#define NT_  16384

#define XG_CAP 1536

typedef unsigned short ushort_t;
typedef __attribute__((ext_vector_type(8))) short short8;
typedef __attribute__((ext_vector_type(4))) float f32x4;

// ---- workspace layout (bytes) ----
#define OFF_XHI     0u          // bf16 hi of xf [NT][512]   16 MB
#define OFF_XLO     16777216u   // bf16 lo                   16 MB
#define OFF_KHI     33554432u   // bf16 hi of k [K][512]      2 MB
#define OFF_KLO     35651584u   //                            2 MB
#define OFF_PM1     37748736u   // per-colblock min1 u64[16][NT]  2 MB
#define OFF_PM2     39845888u   // per-colblock min2 f32[16][NT]  1 MB
#define OFF_XG      37748736u   // fp32 gathered flagged rows (overlays PM1+PM2 after merge)
#define OFF_PACKED  40894464u   // u64[NT] final (dist,idx)  128 KB
#define OFF_FLIST   41025536u   // i32[NT] compacted flagged rows  64 KB
#define OFF_X2      41091072u   // f32[NT]                    64 KB
#define OFF_K2      41156608u   // f32[K]                      8 KB
#define OFF_KRAND   41164800u   // i32[K]  \  single upload region:
#define OFF_SCAL    41172992u   //  [0..3]=sums; int[8]=nflag  \  krand then zeros
#define OFF_COUNTS  41173248u   // f32[K]                      /
#define OFF_CURSOR  41181440u   // i32[K]                     /
#define UPLOAD_LEN  24832u      // 8192 krand + 16640 zeros
#define OFF_OFFS    41443584u   // i32[2049]
#define OFF_ROWL    41452032u   // i32[NT]

// out offsets (floats)
#define O_XL    0u
#define O_XD    16384u
#define O_SC    8404992u
#define O_KNEW  8404997u
#define O_KSN   9453573u
#define O_KEN   10502149u

__device__ __forceinline__ float bf2f(ushort_t u) {
  return __uint_as_float(((unsigned)u) << 16);
}
__device__ __forceinline__ ushort_t f2bf_hw(float v) {
  __hip_bfloat16 h = __float2bfloat16(v);   // HW RN convert; lo pass compensates
  return *reinterpret_cast<ushort_t*>(&h);
}
__device__ __forceinline__ void gload_lds16(const void* g, void* l) {
  __builtin_amdgcn_global_load_lds(
      (const __attribute__((address_space(1))) unsigned*)g,
      (__attribute__((address_space(3))) unsigned*)l, 16, 0, 0);
}

// ---------------- threefry2x32 (jax key schedule) — HOST, krand is input-independent ----------------
static inline void tf2x32_host(uint32_t k0, uint32_t k1, uint32_t x0, uint32_t x1,
                               uint32_t& o0, uint32_t& o1) {
  const uint32_t ks2 = k0 ^ k1 ^ 0x1BD11BDAu;
  x0 += k0; x1 += k1;
#define ROUND4(a,b,c,d) \
  x0+=x1; x1=(x1<<(a))|(x1>>(32-(a))); x1^=x0; \
  x0+=x1; x1=(x1<<(b))|(x1>>(32-(b))); x1^=x0; \
  x0+=x1; x1=(x1<<(c))|(x1>>(32-(c))); x1^=x0; \
  x0+=x1; x1=(x1<<(d))|(x1>>(32-(d))); x1^=x0;
  ROUND4(13,15,26,6)  x0+=k1;  x1+=ks2+1u;
  ROUND4(17,29,16,24) x0+=ks2; x1+=k0+2u;
  ROUND4(13,15,26,6)  x0+=k0;  x1+=k1+3u;
  ROUND4(17,29,16,24) x0+=k1;  x1+=ks2+4u;
  ROUND4(13,15,26,6)  x0+=ks2; x1+=k0+5u;
#undef ROUND4
  o0 = x0; o1 = x1;
}

static int h_upload[UPLOAD_LEN / 4];      // [0..2047]=krand, rest zeros
static bool h_upload_ready = false;

static void compute_krand_host() {
  static uint32_t bits1[NT_], bits2[NT_];
  static uint16_t rank1[NT_], rank2[NT_];
  static int idx[NT_];
  uint32_t a0, a1, b0, b1, c0, c1, d0, d1, o0, o1;
  tf2x32_host(0u, 42u, 0u, 0u, a0, a1);
  tf2x32_host(0u, 42u, 0u, 1u, b0, b1);
  tf2x32_host(a0, a1, 0u, 0u, c0, c1);
  tf2x32_host(a0, a1, 0u, 1u, d0, d1);
  (void)c0; (void)c1;
  for (uint32_t i = 0; i < NT_; i++) {
    tf2x32_host(b0, b1, 0u, i, o0, o1); bits1[i] = o1;
    tf2x32_host(d0, d1, 0u, i, o0, o1); bits2[i] = o1;
  }
  for (int i = 0; i < NT_; i++) idx[i] = i;
  std::stable_sort(idx, idx + NT_, [&](int a, int b) { return bits1[a] < bits1[b]; });
  for (int pos = 0; pos < NT_; pos++) rank1[idx[pos]] = (uint16_t)pos;
  for (int i = 0; i < NT_; i++) idx[i] = i;
  std::stable_sort(idx, idx + NT_, [&](int a, int b) { return bits2[a] < bits2[b]; });
  for (int pos = 0; pos < NT_; pos++) rank2[idx[pos]] = (uint16_t)pos;
  for (int i = 0; i < (int)(UPLOAD_LEN / 4); i++) h_upload[i] = 0;
  for (int i = 0; i < NT_; i++) {
    int j = rank1[i] & 16383;
    int p = rank2[j];
    if (p < K_) h_upload[p] = i;
  }
}

// ---------------- fused prep: blocks [0,256) = x path, [256,512) = k path ----------------
__global__ void vq_prep(const float* __restrict__ x, const float* __restrict__ k,
                        ushort_t* __restrict__ xhi, ushort_t* __restrict__ xlo,
                        float* __restrict__ x2, float* __restrict__ scal,
                        ushort_t* __restrict__ khi, ushort_t* __restrict__ klo,
                        float* __restrict__ k2v) {
  __shared__ float tile[64][65];
  __shared__ float x2s[64];
  __shared__ float rs[4], rq[4];
  int tid = threadIdx.x;
  if (blockIdx.x >= 256) {
    // ---- k path ----
    int row = (blockIdx.x - 256) * 8 + (tid >> 5);
    int wl = tid & 31;
    const float* kr = k + (size_t)row * 512;
    float acc = 0.f;
#pragma unroll
    for (int c = 0; c < 4; c++) {
      int w = c * 128 + wl * 4;
      float4 v = *(const float4*)(kr + w);
      ushort4 hv, lv;
      hv.x = f2bf_hw(v.x); lv.x = f2bf_hw(v.x - bf2f(hv.x));
      hv.y = f2bf_hw(v.y); lv.y = f2bf_hw(v.y - bf2f(hv.y));
      hv.z = f2bf_hw(v.z); lv.z = f2bf_hw(v.z - bf2f(hv.z));
      hv.w = f2bf_hw(v.w); lv.w = f2bf_hw(v.w - bf2f(hv.w));
      *(ushort4*)&khi[(size_t)row * 512 + w] = hv;
      *(ushort4*)&klo[(size_t)row * 512 + w] = lv;
      acc += v.x * v.x + v.y * v.y + v.z * v.z + v.w * v.w;
    }
    for (int off = 16; off; off >>= 1) acc += __shfl_down(acc, off, 32);
    if (wl == 0) k2v[row] = acc;
    return;
  }
  // ---- x path ----
  int b = blockIdx.x;
  int n = b >> 4, tc = b & 15;
  int t0 = tc * 64;
  if (tid < 64) x2s[tid] = 0.f;
  __syncthreads();
  float gs = 0.f, gq = 0.f;
  const size_t xb = (size_t)n * (W_ * T_);
  int tqs = tid & 15, wgs = tid >> 4;       // staging: t-quad, w lane
  int wl4 = 4 * (tid & 15), tg = tid >> 4;  // compute: 4 cols/thread, t group
  for (int p = 0; p < 8; p++) {
    int w0 = p * 64;
    // stage: float4 along t (x contiguous in t) -> 4 loads/thread
#pragma unroll
    for (int s = 0; s < 4; s++) {
      int w = s * 16 + wgs;
      float4 v = *(const float4*)&x[xb + (size_t)(w0 + w) * T_ + t0 + tqs * 4];
      tile[tqs * 4 + 0][w] = v.x;
      tile[tqs * 4 + 1][w] = v.y;
      tile[tqs * 4 + 2][w] = v.z;
      tile[tqs * 4 + 3][w] = v.w;
    }
    __syncthreads();
    // compute: thread owns cols wl4..wl4+3 of row t -> ushort4 stores
#pragma unroll
    for (int s = 0; s < 4; s++) {
      int t = s * 16 + tg;
      float v0 = tile[t][wl4 + 0], v1 = tile[t][wl4 + 1];
      float v2 = tile[t][wl4 + 2], v3 = tile[t][wl4 + 3];
      ushort4 hv, lv;
      hv.x = f2bf_hw(v0); lv.x = f2bf_hw(v0 - bf2f(hv.x));
      hv.y = f2bf_hw(v1); lv.y = f2bf_hw(v1 - bf2f(hv.y));
      hv.z = f2bf_hw(v2); lv.z = f2bf_hw(v2 - bf2f(hv.z));
      hv.w = f2bf_hw(v3); lv.w = f2bf_hw(v3 - bf2f(hv.w));
      size_t row = (size_t)n * 1024 + t0 + t;
      *(ushort4*)&xhi[row * 512 + w0 + wl4] = hv;
      *(ushort4*)&xlo[row * 512 + w0 + wl4] = lv;
      gs += v0 + v1 + v2 + v3;
      float part = v0 * v0 + v1 * v1 + v2 * v2 + v3 * v3;
      gq += part;
      for (int off = 8; off; off >>= 1) part += __shfl_down(part, off, 16);
      if ((tid & 15) == 0) x2s[t] += part;
    }
    __syncthreads();
  }
  for (int off = 32; off; off >>= 1) { gs += __shfl_down(gs, off, 64); gq += __shfl_down(gq, off, 64); }
  if ((tid & 63) == 0) { rs[tid >> 6] = gs; rq[tid >> 6] = gq; }
  __syncthreads();
  if (tid == 0) {
    atomicAdd(&scal[0], rs[0] + rs[1] + rs[2] + rs[3]);
    atomicAdd(&scal[1], rq[0] + rq[1] + rq[2] + rq[3]);
  }
  if (tid < 64) x2[n * 1024 + t0 + tid] = x2s[tid];
}

// ---------------- MFMA argmin: 128x128 tile, BK=64, split-bf16 3-term ----------------
// K-loop FROZEN: round-7 structure + addressing, HW-validated conflict-free.
// Epilogue (post K-loop): parallel 256-thread merge (R15) — bit-identical output.
__global__ __launch_bounds__(256, 2) void vq_argmin_mfma(
    const ushort_t* __restrict__ xhi, const ushort_t* __restrict__ xlo,
    const ushort_t* __restrict__ khi, const ushort_t* __restrict__ klo,
    const float* __restrict__ x2, const float* __restrict__ k2,
    unsigned long long* __restrict__ pm1, float* __restrict__ pm2) {
  __shared__ __align__(16) char smem[65536];
  int tid = threadIdx.x;
  int bx = blockIdx.x & 127, by = blockIdx.x >> 7;
  int row0 = bx * 128, col0 = by * 128;
  int lane = tid & 63, wid = tid >> 6;
  int wm = wid >> 1, wn = wid & 1;
  int lr = lane & 15, quad = lane >> 4;

  const char* gb[4];
  gb[0] = (const char*)xhi + (size_t)row0 * 1024;
  gb[1] = (const char*)xlo + (size_t)row0 * 1024;
  gb[2] = (const char*)khi + (size_t)col0 * 1024;
  gb[3] = (const char*)klo + (size_t)col0 * 1024;
  uint32_t goff[4], loff[4];
#pragma unroll
  for (int it = 0; it < 4; it++) {
    int cid = it * 256 + tid;
    int row = cid >> 3;
    int cc = (cid & 7) ^ (row & 7);
    goff[it] = row * 1024 + cc * 16;
    loff[it] = cid * 16;
  }
  uint32_t aoff[4], boff[4];
#pragma unroll
  for (int i = 0; i < 4; i++) {
    int ra = wm * 64 + i * 16 + lr;
    aoff[i] = ra * 128 + ((quad ^ (ra & 7)) * 16);
    int rb = wn * 64 + i * 16 + lr;
    boff[i] = rb * 128 + ((quad ^ (rb & 7)) * 16);
  }
  f32x4 acc[4][4] = {};

  for (int kt = 0; kt < 8; kt++) {
    uint32_t kofs = (uint32_t)kt * 128;
#pragma unroll
    for (int tl = 0; tl < 4; tl++)
#pragma unroll
      for (int it = 0; it < 4; it++)
        gload_lds16(gb[tl] + goff[it] + kofs, &smem[tl * 16384 + loff[it]]);
    __syncthreads();
#pragma unroll
    for (int kk = 0; kk < 2; kk++) {
      uint32_t kx = (uint32_t)kk << 6;
      short8 ah[4], al[4], bh[4], bl[4];
#pragma unroll
      for (int i = 0; i < 4; i++) {
        ah[i] = *(const short8*)&smem[(aoff[i] ^ kx)];
        al[i] = *(const short8*)&smem[16384 + (aoff[i] ^ kx)];
        bh[i] = *(const short8*)&smem[32768 + (boff[i] ^ kx)];
        bl[i] = *(const short8*)&smem[49152 + (boff[i] ^ kx)];
      }
#pragma unroll
      for (int i = 0; i < 4; i++)
#pragma unroll
        for (int j = 0; j < 4; j++) {
          acc[i][j] = __builtin_amdgcn_mfma_f32_16x16x32_bf16(ah[i], bh[j], acc[i][j], 0, 0, 0);
          acc[i][j] = __builtin_amdgcn_mfma_f32_16x16x32_bf16(ah[i], bl[j], acc[i][j], 0, 0, 0);
          acc[i][j] = __builtin_amdgcn_mfma_f32_16x16x32_bf16(al[i], bh[j], acc[i][j], 0, 0, 0);
        }
    }
    __syncthreads();
  }

  // epilogue: per-row top-2 into LDS [128][33] (padded), then PARALLEL 32-slot merge
  unsigned long long* L1 = (unsigned long long*)smem;   // [128][33] u64, 33792 B
  float* L2f = (float*)&smem[33792];                    // [128][33] f32, 16896 B
  unsigned long long* P1 = (unsigned long long*)&smem[50688];  // [128] u64, 1024 B
  float* P2 = (float*)&smem[51712];                            // [128] f32,  512 B
  float k2c[4];
#pragma unroll
  for (int j = 0; j < 4; j++) k2c[j] = k2[col0 + wn * 64 + j * 16 + lr];
#pragma unroll
  for (int i = 0; i < 4; i++) {
#pragma unroll
    for (int r = 0; r < 4; r++) {
      int row_l = wm * 64 + i * 16 + quad * 4 + r;
      float x2r = x2[row0 + row_l];
      float m1 = 3.4e38f, m2 = 3.4e38f; int mi = 0;
#pragma unroll
      for (int j = 0; j < 4; j++) {
        float d = (x2r - 2.0f * acc[i][j][r]) + k2c[j];
        int kg = col0 + wn * 64 + j * 16 + lr;
        if (d < m1) { m2 = m1; m1 = d; mi = kg; } else m2 = fminf(m2, d);
      }
      L1[row_l * 33 + wn * 16 + lr] =
          (((unsigned long long)__float_as_uint(m1)) << 32) | (unsigned)mi;
      L2f[row_l * 33 + wn * 16 + lr] = m2;
    }
  }
  __syncthreads();
  {
    int row = tid & 127;
    int half = tid >> 7;               // 0: slots 0-15, 1: slots 16-31
    int base = row * 33 + half * 16;
    unsigned long long b1 = L1[base];
    float b2 = L2f[base];
    for (int c = 1; c < 16; c++) {
      unsigned long long v = L1[base + c];
      float vf = L2f[base + c];
      if (v < b1) { b2 = fminf(b2, __uint_as_float((unsigned)(b1 >> 32))); b1 = v; }
      else b2 = fminf(b2, __uint_as_float((unsigned)(v >> 32)));
      b2 = fminf(b2, vf);
    }
    if (half) { P1[row] = b1; P2[row] = b2; }
    __syncthreads();
    if (!half) {
      unsigned long long o1 = P1[row];
      float o2 = P2[row];
      if (o1 < b1) { b2 = fminf(b2, __uint_as_float((unsigned)(b1 >> 32))); b1 = o1; }
      else b2 = fminf(b2, __uint_as_float((unsigned)(o1 >> 32)));
      b2 = fminf(b2, o2);
      pm1[(size_t)by * NT_ + row0 + row] = b1;
      pm2[(size_t)by * NT_ + row0 + row] = b2;
    }
  }
}

// ---------------- merge 16 col-blocks -> packed + compacted near-tie list ----------------
__global__ void vq_merge(const unsigned long long* __restrict__ pm1,
                         const float* __restrict__ pm2,
                         unsigned long long* __restrict__ packed,
                         int* __restrict__ flist, int* __restrict__ nflag) {
  int r = blockIdx.x * 256 + threadIdx.x;
  unsigned long long b1 = pm1[r];
  float b2 = pm2[r];
  for (int c = 1; c < 16; c++) {
    unsigned long long v = pm1[(size_t)c * NT_ + r];
    float vf = pm2[(size_t)c * NT_ + r];
    if (v < b1) { b2 = fminf(b2, __uint_as_float((unsigned)(b1 >> 32))); b1 = v; }
    else b2 = fminf(b2, __uint_as_float((unsigned)(v >> 32)));
    b2 = fminf(b2, vf);
  }
  if ((b2 - __uint_as_float((unsigned)(b1 >> 32))) < 3e-4f) {
    packed[r] = 0xFFFFFFFFFFFFFFFFull;
    int pos = atomicAdd(nflag, 1);
    flist[pos] = r;
  } else {
    packed[r] = b1;
  }
}

// ---------------- gather flagged x rows to dense fp32 (coalesced writes) ----------------
__global__ void vq_gatherx(const float* __restrict__ x, const int* __restrict__ flist,
                           const int* __restrict__ nflag, float* __restrict__ xg) {
  int nf = *nflag; if (nf > XG_CAP) nf = XG_CAP;
  int total = nf * 512;
  for (int e = blockIdx.x * 256 + threadIdx.x; e < total; e += gridDim.x * 256) {
    int ii = e >> 9, c = e & 511;
    int r = flist[ii];
    xg[e] = x[(size_t)(r >> 10) * 524288 + (size_t)c * 1024 + (r & 1023)];
  }
}

// ---------------- fp32 exact repair: (8-row group) x (256-cluster chunk) ----------------
__global__ void vq_repair(const float* __restrict__ x, const float* __restrict__ k,
                          const float* __restrict__ xg,
                          const float* __restrict__ x2, const float* __restrict__ k2,
                          const int* __restrict__ flist, const int* __restrict__ nflag,
                          unsigned long long* __restrict__ packed) {
  __shared__ float xs[8][512];
  __shared__ unsigned long long part[8][4];
  int tid = threadIdx.x;
  int lane = tid & 63, wave = tid >> 6;
  int nf = *nflag;
  int ngrp = (nf + 7) >> 3;
  int nwork = ngrp * 8;
  for (int wi = blockIdx.x; wi < nwork; wi += gridDim.x) {
    int g = wi >> 3, c = wi & 7;
    int base = g * 8;
    for (int e = tid; e < 8 * 512; e += 256) {
      int rr = e >> 9, cc = e & 511;
      int ii = base + rr;
      float v = 0.f;
      if (ii < nf) {
        if (ii < XG_CAP) v = xg[ii * 512 + cc];
        else { int r = flist[ii]; v = x[(size_t)(r >> 10) * 524288 + (size_t)cc * 1024 + (r & 1023)]; }
      }
      xs[rr][cc] = v;
    }
    __syncthreads();
    int j = c * 256 + tid;
    const float4* kr = (const float4*)(k + (size_t)j * 512);
    float dot[8] = {0.f, 0.f, 0.f, 0.f, 0.f, 0.f, 0.f, 0.f};
    for (int w4 = 0; w4 < 128; w4++) {
      float4 kv = kr[w4];
#pragma unroll
      for (int rr = 0; rr < 8; rr++) {
        const float4 xv = *(const float4*)&xs[rr][w4 * 4];
        dot[rr] = fmaf(xv.x, kv.x, dot[rr]);
        dot[rr] = fmaf(xv.y, kv.y, dot[rr]);
        dot[rr] = fmaf(xv.z, kv.z, dot[rr]);
        dot[rr] = fmaf(xv.w, kv.w, dot[rr]);
      }
    }
    float k2j = k2[j];
#pragma unroll
    for (int rr = 0; rr < 8; rr++) {
      int ii = base + rr;
      unsigned long long pv = 0xFFFFFFFFFFFFFFFFull;
      if (ii < nf) {
        int r = flist[ii];
        float d = (x2[r] - 2.0f * dot[rr]) + k2j;
        pv = (((unsigned long long)__float_as_uint(d)) << 32) | (unsigned)j;
      }
      for (int off = 32; off; off >>= 1) {
        unsigned long long o = __shfl_down(pv, off, 64);
        if (o < pv) pv = o;
      }
      if (lane == 0) part[rr][wave] = pv;
    }
    __syncthreads();
    if (tid < 8) {
      int ii = base + tid;
      if (ii < nf) {
        unsigned long long m = part[tid][0];
        if (part[tid][1] < m) m = part[tid][1];
        if (part[tid][2] < m) m = part[tid][2];
        if (part[tid][3] < m) m = part[tid][3];
        atomicMin(&packed[flist[ii]], m);
      }
    }
    __syncthreads();
  }
}

// ---------------- x_l, counts, fit ----------------
__global__ void vq_cnt2(const unsigned long long* __restrict__ packed,
                        float* __restrict__ counts, float* __restrict__ scal,
                        float* __restrict__ out) {
  int tid = threadIdx.x;
  int r = blockIdx.x * 256 + tid;
  unsigned long long p = packed[r];
  unsigned idx = (unsigned)(p & 0xFFFFFFFFull);
  float md = __uint_as_float((unsigned)(p >> 32));
  out[O_XL + r] = (float)idx;
  atomicAdd(&counts[idx], 1.0f);
  float s = md;
  for (int off = 32; off; off >>= 1) s += __shfl_down(s, off, 64);
  __shared__ float rs[4];
  if ((tid & 63) == 0) rs[tid >> 6] = s;
  __syncthreads();
  if (tid == 0) atomicAdd(&scal[2], rs[0] + rs[1] + rs[2] + rs[3]);
}

// ---------------- exclusive scan of counts -> offsets (parallel wave scan) ----------------
__global__ void vq_scan(const float* __restrict__ counts, int* __restrict__ offs) {
  __shared__ int wsum[4];
  int t = threadIdx.x;
  int loc[8];
  int s = 0;
#pragma unroll
  for (int c = 0; c < 8; c++) { loc[c] = (int)counts[t * 8 + c]; s += loc[c]; }
  int orig = s;
  int lane = t & 63, wave = t >> 6;
#pragma unroll
  for (int off = 1; off < 64; off <<= 1) {
    int v = __shfl_up(s, off, 64);
    if (lane >= off) s += v;
  }
  if (lane == 63) wsum[wave] = s;
  __syncthreads();
  int add = 0;
  for (int w = 0; w < 4; w++) if (w < wave) add += wsum[w];
  int excl = s + add - orig;
#pragma unroll
  for (int c = 0; c < 8; c++) {
    offs[t * 8 + c] = excl;
    excl += loc[c];
  }
  if (t == 255) offs[2048] = excl;
}

// ---------------- fused: CSR fill (blocks 0..63) + x_d gather/store (blocks 64..1087) ----------------
__global__ void vq_fill_xd(const unsigned long long* __restrict__ packed,
                           const int* __restrict__ offs, int* __restrict__ cursor,
                           int* __restrict__ rowl, const float* __restrict__ k,
                           float* __restrict__ out) {
  __shared__ int lrow[64];
  int tid = threadIdx.x;
  if (blockIdx.x < 64) {
    int r = blockIdx.x * 256 + tid;
    int idx = (int)(packed[r] & 0xFFFFFFFFull);
    int pos = atomicAdd(&cursor[idx], 1);
    rowl[offs[idx] + pos] = r;
    return;
  }
  int bid = blockIdx.x - 64;
  int tb = bid >> 2, wq = bid & 3;        // tb: 0..255 (64-row t-blocks), wq: 128-w quarter
  int row0 = tb * 64;
  int n = row0 >> 10, t0 = row0 & 1023;
  if (tid < 64) lrow[tid] = (int)(packed[row0 + tid] & 0xFFFFFFFFull);
  __syncthreads();
  int tq = (tid & 15) * 4;                // t offset within 64 (quad)
  int wl = tid >> 4;                      // 0..15
  const float* k0 = k + (size_t)lrow[tq + 0] * 512;
  const float* k1 = k + (size_t)lrow[tq + 1] * 512;
  const float* k2r = k + (size_t)lrow[tq + 2] * 512;
  const float* k3 = k + (size_t)lrow[tq + 3] * 512;
  float* xd = out + O_XD + (size_t)n * 524288 + t0 + tq;
#pragma unroll
  for (int it = 0; it < 8; it++) {
    int w = wq * 128 + it * 16 + wl;
    float4 v;
    v.x = k0[w]; v.y = k1[w]; v.z = k2r[w]; v.w = k3[w];
    *(float4*)&xd[(size_t)w * 1024] = v;
  }
}

// ---------------- codebook EMA update via CSR gather (8B loads, row-parity split) ----------------
__global__ void vq_knew_csr(const ushort_t* __restrict__ xhi, const ushort_t* __restrict__ xlo,
                            const float* __restrict__ k, const float* __restrict__ ksum_in,
                            const float* __restrict__ kelem_in, const int* __restrict__ offs,
                            const int* __restrict__ rowl, const int* __restrict__ krand,
                            float* __restrict__ out, float* __restrict__ scal) {
  __shared__ float4 sb[128];
  __shared__ float r4[4];
  int j = blockIdx.x, tid = threadIdx.x;
  int o0 = offs[j], o1 = offs[j + 1];
  int c = tid & 127;                      // col group: owns w0..w0+3
  int g = tid >> 7;                       // row parity
  int w0 = c * 4;
  float s0 = 0.f, s1 = 0.f, s2 = 0.f, s3 = 0.f;
  for (int p = o0 + g; p < o1; p += 2) {
    int r = rowl[p];
    uint2 ha = *(const uint2*)&xhi[(size_t)r * 512 + w0];
    uint2 la = *(const uint2*)&xlo[(size_t)r * 512 + w0];
    s0 += bf2f((ushort_t)ha.x) + bf2f((ushort_t)la.x);
    s1 += bf2f((ushort_t)(ha.x >> 16)) + bf2f((ushort_t)(la.x >> 16));
    s2 += bf2f((ushort_t)ha.y) + bf2f((ushort_t)la.y);
    s3 += bf2f((ushort_t)(ha.y >> 16)) + bf2f((ushort_t)(la.y >> 16));
  }
  if (g) { sb[c].x = s0; sb[c].y = s1; sb[c].z = s2; sb[c].w = s3; }
  __syncthreads();
  float cnt = (float)(o1 - o0);
  float ken = 0.99f * kelem_in[j] + 0.01f * cnt;
  bool use = (ken >= 1.0f);
  int ir = krand[j] & 16383;
  float dd = 0.f;
  if (!g) {
    float4 ps = sb[c];
    s0 += ps.x; s1 += ps.y; s2 += ps.z; s3 += ps.w;
    float4 ks = *(const float4*)&ksum_in[(size_t)j * 512 + w0];
    float4 kc = *(const float4*)&k[(size_t)j * 512 + w0];
    float ksn0 = 0.99f * ks.x + 0.01f * s0;
    float ksn1 = 0.99f * ks.y + 0.01f * s1;
    float ksn2 = 0.99f * ks.z + 0.01f * s2;
    float ksn3 = 0.99f * ks.w + 0.01f * s3;
    size_t ob = (size_t)j * 512 + w0;
    out[O_KSN + ob + 0] = ksn0;           // O_KSN/O_KNEW odd float offsets: scalar stores
    out[O_KSN + ob + 1] = ksn1;
    out[O_KSN + ob + 2] = ksn2;
    out[O_KSN + ob + 3] = ksn3;
    float kn0, kn1, kn2, kn3;
    if (use) {
      float inv = 1.0f / ken;
      kn0 = ksn0 * inv; kn1 = ksn1 * inv; kn2 = ksn2 * inv; kn3 = ksn3 * inv;
    } else {
      uint2 hr = *(const uint2*)&xhi[(size_t)ir * 512 + w0];
      uint2 lr = *(const uint2*)&xlo[(size_t)ir * 512 + w0];
      kn0 = bf2f((ushort_t)hr.x) + bf2f((ushort_t)lr.x);
      kn1 = bf2f((ushort_t)(hr.x >> 16)) + bf2f((ushort_t)(lr.x >> 16));
      kn2 = bf2f((ushort_t)hr.y) + bf2f((ushort_t)lr.y);
      kn3 = bf2f((ushort_t)(hr.y >> 16)) + bf2f((ushort_t)(lr.y >> 16));
    }
    out[O_KNEW + ob + 0] = kn0;
    out[O_KNEW + ob + 1] = kn1;
    out[O_KNEW + ob + 2] = kn2;
    out[O_KNEW + ob + 3] = kn3;
    float d0 = kn0 - kc.x, d1 = kn1 - kc.y, d2 = kn2 - kc.z, d3 = kn3 - kc.w;
    dd = d0 * d0 + d1 * d1 + d2 * d2 + d3 * d3;
  }
  for (int off = 32; off; off >>= 1) dd += __shfl_down(dd, off, 64);
  if ((tid & 63) == 0) r4[tid >> 6] = dd;
  __syncthreads();
  if (tid == 0) {
    atomicAdd(&scal[3], r4[0] + r4[1] + r4[2] + r4[3]);
    out[O_KEN + j] = ken;
  }
}

// ---------------- scalars ----------------
__global__ void vq_fin(const float* __restrict__ counts, const float* __restrict__ scal,
                       float* __restrict__ out) {
  int tid = threadIdx.x;
  float e = 0.f;
  for (int j = tid; j < K_; j += 256) {
    float p = counts[j] * (1.0f / 16384.0f);
    e -= p * logf(p + 1e-8f);
  }
  for (int off = 32; off; off >>= 1) e += __shfl_down(e, off, 64);
  __shared__ float r[4];
  if ((tid & 63) == 0) r[tid >> 6] = e;
  __syncthreads();
  if (tid == 0) {
    float ent = r[0] + r[1] + r[2] + r[3];
    float sum = scal[0], sumsq = scal[1], fits = scal[2], d2 = scal[3];
    const float S = 8388608.f;
    out[O_SC + 0] = fits / S;
    out[O_SC + 1] = fits / 16384.f;
    out[O_SC + 2] = sqrtf((sumsq - sum * sum / S) / S);
    out[O_SC + 3] = ent;
    out[O_SC + 4] = sqrtf(d2 / 1048576.f);
  }
}

extern "C" void kernel_launch(void* const* d_in, const int* in_sizes, int n_in,
                              void* d_out, int out_size, void* d_ws, size_t ws_size,
                              hipStream_t stream) {
  (void)in_sizes; (void)n_in; (void)out_size; (void)ws_size;
  const float* x        = (const float*)d_in[0];
  const float* k        = (const float*)d_in[1];
  const float* ksum_in  = (const float*)d_in[2];
  const float* kelem_in = (const float*)d_in[3];
  float* out = (float*)d_out;
  uint8_t* ws = (uint8_t*)d_ws;

  ushort_t* xhi = (ushort_t*)(ws + OFF_XHI);
  ushort_t* xlo = (ushort_t*)(ws + OFF_XLO);
  ushort_t* khi = (ushort_t*)(ws + OFF_KHI);
  ushort_t* klo = (ushort_t*)(ws + OFF_KLO);
  unsigned long long* pm1 = (unsigned long long*)(ws + OFF_PM1);
  float*    pm2    = (float*)(ws + OFF_PM2);
  float*    xg     = (float*)(ws + OFF_XG);
  unsigned long long* packed = (unsigned long long*)(ws + OFF_PACKED);
  int*      flist  = (int*)(ws + OFF_FLIST);
  float*    x2v    = (float*)(ws + OFF_X2);
  float*    k2v    = (float*)(ws + OFF_K2);
  float*    scal   = (float*)(ws + OFF_SCAL);
  int*      nflag  = (int*)(ws + OFF_SCAL + 32);
  float*    counts = (float*)(ws + OFF_COUNTS);
  int*      cursor = (int*)(ws + OFF_CURSOR);
  int*      offs   = (int*)(ws + OFF_OFFS);
  int*      rowl   = (int*)(ws + OFF_ROWL);
  int*      krand  = (int*)(ws + OFF_KRAND);

  if (!h_upload_ready) { compute_krand_host(); h_upload_ready = true; }

  // single upload: krand (8KB) + zeros for SCAL/COUNTS/CURSOR (16.6KB)
  hipMemcpyAsync(ws + OFF_KRAND, h_upload, UPLOAD_LEN, hipMemcpyHostToDevice, stream);

  vq_prep<<<512, 256, 0, stream>>>(x, k, xhi, xlo, x2v, scal, khi, klo, k2v);
  vq_argmin_mfma<<<2048, 256, 0, stream>>>(xhi, xlo, khi, klo, x2v, k2v, pm1, pm2);
  vq_merge<<<64, 256, 0, stream>>>(pm1, pm2, packed, flist, nflag);
  vq_gatherx<<<256, 256, 0, stream>>>(x, flist, nflag, xg);
  vq_repair<<<512, 256, 0, stream>>>(x, k, xg, x2v, k2v, flist, nflag, packed);
  vq_cnt2<<<64, 256, 0, stream>>>(packed, counts, scal, out);
  vq_scan<<<1, 256, 0, stream>>>(counts, offs);
  vq_fill_xd<<<1088, 256, 0, stream>>>(packed, offs, cursor, rowl, k, out);
  vq_knew_csr<<<2048, 256, 0, stream>>>(xhi, xlo, k, ksum_in, kelem_in, offs, rowl, krand, out, scal);
  vq_fin<<<1, 256, 0, stream>>>(counts, scal, out);
}

// Round 10
// 293.850 us; speedup vs baseline: 1.0598x; 1.0598x over previous
//
#include <hip/hip_runtime.h>
#include <hip/hip_bf16.h>
#include <stdint.h>
#include <algorithm>

// VQ-VAE quantise round. N=16, W=512, T=1024, K=2048, NT=16384.
// Round 17: round-16 resubmit (compile fix: trailing backslash in a comment had
// swallowed the OFF_COUNTS define). Launch path: device memset for zeros (fast
// device-side node; R13's 24.8KB pageable-host memcpy node was the +7us drift)
// + 8KB krand memcpy. Kernels: R12 prep/knew_csr; argmin frozen K-loop + R15
// parallel epilogue (bit-identical).

#define W_   512
#define T_   1024
#define K_   2048
#define NT_  16384

#define XG_CAP 1536

typedef unsigned short ushort_t;
typedef __attribute__((ext_vector_type(8))) short short8;
typedef __attribute__((ext_vector_type(4))) float f32x4;

// ---- workspace layout (bytes) ----
#define OFF_XHI     0u          // bf16 hi of xf [NT][512]   16 MB
#define OFF_XLO     16777216u   // bf16 lo                   16 MB
#define OFF_KHI     33554432u   // bf16 hi of k [K][512]      2 MB
#define OFF_KLO     35651584u   //                            2 MB
#define OFF_PM1     37748736u   // per-colblock min1 u64[16][NT]  2 MB
#define OFF_PM2     39845888u   // per-colblock min2 f32[16][NT]  1 MB
#define OFF_XG      37748736u   // fp32 gathered flagged rows (overlays PM1+PM2 after merge)
#define OFF_PACKED  40894464u   // u64[NT] final (dist,idx)  128 KB
#define OFF_FLIST   41025536u   // i32[NT] compacted flagged rows  64 KB
#define OFF_X2      41091072u   // f32[NT]                    64 KB
#define OFF_K2      41156608u   // f32[K]                      8 KB
#define OFF_KRAND   41164800u   // i32[K]  (8KB memcpy from host)
#define OFF_SCAL    41172992u   // [0..3]=sums; int[8]=nflag  (memset region start)
#define OFF_COUNTS  41173248u   // f32[K]   (memset)
#define OFF_CURSOR  41181440u   // i32[K]   (memset region end)
#define ZERO_LEN    16640u
#define OFF_OFFS    41443584u   // i32[2049]
#define OFF_ROWL    41452032u   // i32[NT]

// out offsets (floats)
#define O_XL    0u
#define O_XD    16384u
#define O_SC    8404992u
#define O_KNEW  8404997u
#define O_KSN   9453573u
#define O_KEN   10502149u

__device__ __forceinline__ float bf2f(ushort_t u) {
  return __uint_as_float(((unsigned)u) << 16);
}
__device__ __forceinline__ ushort_t f2bf_hw(float v) {
  __hip_bfloat16 h = __float2bfloat16(v);   // HW RN convert; lo pass compensates
  return *reinterpret_cast<ushort_t*>(&h);
}
__device__ __forceinline__ void gload_lds16(const void* g, void* l) {
  __builtin_amdgcn_global_load_lds(
      (const __attribute__((address_space(1))) unsigned*)g,
      (__attribute__((address_space(3))) unsigned*)l, 16, 0, 0);
}

// ---------------- threefry2x32 (jax key schedule) — HOST, krand is input-independent ----------------
static inline void tf2x32_host(uint32_t k0, uint32_t k1, uint32_t x0, uint32_t x1,
                               uint32_t& o0, uint32_t& o1) {
  const uint32_t ks2 = k0 ^ k1 ^ 0x1BD11BDAu;
  x0 += k0; x1 += k1;
#define ROUND4(a,b,c,d) \
  x0+=x1; x1=(x1<<(a))|(x1>>(32-(a))); x1^=x0; \
  x0+=x1; x1=(x1<<(b))|(x1>>(32-(b))); x1^=x0; \
  x0+=x1; x1=(x1<<(c))|(x1>>(32-(c))); x1^=x0; \
  x0+=x1; x1=(x1<<(d))|(x1>>(32-(d))); x1^=x0;
  ROUND4(13,15,26,6)  x0+=k1;  x1+=ks2+1u;
  ROUND4(17,29,16,24) x0+=ks2; x1+=k0+2u;
  ROUND4(13,15,26,6)  x0+=k0;  x1+=k1+3u;
  ROUND4(17,29,16,24) x0+=k1;  x1+=ks2+4u;
  ROUND4(13,15,26,6)  x0+=ks2; x1+=k0+5u;
#undef ROUND4
  o0 = x0; o1 = x1;
}

static int h_krand[K_];
static bool h_krand_ready = false;

static void compute_krand_host() {
  static uint32_t bits1[NT_], bits2[NT_];
  static uint16_t rank1[NT_], rank2[NT_];
  static int idx[NT_];
  uint32_t a0, a1, b0, b1, c0, c1, d0, d1, o0, o1;
  tf2x32_host(0u, 42u, 0u, 0u, a0, a1);
  tf2x32_host(0u, 42u, 0u, 1u, b0, b1);
  tf2x32_host(a0, a1, 0u, 0u, c0, c1);
  tf2x32_host(a0, a1, 0u, 1u, d0, d1);
  (void)c0; (void)c1;
  for (uint32_t i = 0; i < NT_; i++) {
    tf2x32_host(b0, b1, 0u, i, o0, o1); bits1[i] = o1;
    tf2x32_host(d0, d1, 0u, i, o0, o1); bits2[i] = o1;
  }
  for (int i = 0; i < NT_; i++) idx[i] = i;
  std::stable_sort(idx, idx + NT_, [&](int a, int b) { return bits1[a] < bits1[b]; });
  for (int pos = 0; pos < NT_; pos++) rank1[idx[pos]] = (uint16_t)pos;
  for (int i = 0; i < NT_; i++) idx[i] = i;
  std::stable_sort(idx, idx + NT_, [&](int a, int b) { return bits2[a] < bits2[b]; });
  for (int pos = 0; pos < NT_; pos++) rank2[idx[pos]] = (uint16_t)pos;
  for (int i = 0; i < NT_; i++) {
    int j = rank1[i] & 16383;
    int p = rank2[j];
    if (p < K_) h_krand[p] = i;
  }
}

// ---------------- fused prep: blocks [0,256) = x path, [256,512) = k path ----------------
__global__ void vq_prep(const float* __restrict__ x, const float* __restrict__ k,
                        ushort_t* __restrict__ xhi, ushort_t* __restrict__ xlo,
                        float* __restrict__ x2, float* __restrict__ scal,
                        ushort_t* __restrict__ khi, ushort_t* __restrict__ klo,
                        float* __restrict__ k2v) {
  __shared__ float tile[64][65];
  __shared__ float x2s[64];
  __shared__ float rs[4], rq[4];
  int tid = threadIdx.x;
  if (blockIdx.x >= 256) {
    // ---- k path ----
    int row = (blockIdx.x - 256) * 8 + (tid >> 5);
    int wl = tid & 31;
    const float* kr = k + (size_t)row * 512;
    float acc = 0.f;
#pragma unroll
    for (int c = 0; c < 4; c++) {
      int w = c * 128 + wl * 4;
      float4 v = *(const float4*)(kr + w);
      ushort4 hv, lv;
      hv.x = f2bf_hw(v.x); lv.x = f2bf_hw(v.x - bf2f(hv.x));
      hv.y = f2bf_hw(v.y); lv.y = f2bf_hw(v.y - bf2f(hv.y));
      hv.z = f2bf_hw(v.z); lv.z = f2bf_hw(v.z - bf2f(hv.z));
      hv.w = f2bf_hw(v.w); lv.w = f2bf_hw(v.w - bf2f(hv.w));
      *(ushort4*)&khi[(size_t)row * 512 + w] = hv;
      *(ushort4*)&klo[(size_t)row * 512 + w] = lv;
      acc += v.x * v.x + v.y * v.y + v.z * v.z + v.w * v.w;
    }
    for (int off = 16; off; off >>= 1) acc += __shfl_down(acc, off, 32);
    if (wl == 0) k2v[row] = acc;
    return;
  }
  // ---- x path ----
  int b = blockIdx.x;
  int n = b >> 4, tc = b & 15;
  int t0 = tc * 64;
  if (tid < 64) x2s[tid] = 0.f;
  __syncthreads();
  float gs = 0.f, gq = 0.f;
  const size_t xb = (size_t)n * (W_ * T_);
  int tqs = tid & 15, wgs = tid >> 4;       // staging: t-quad, w lane
  int wl4 = 4 * (tid & 15), tg = tid >> 4;  // compute: 4 cols/thread, t group
  for (int p = 0; p < 8; p++) {
    int w0 = p * 64;
    // stage: float4 along t (x contiguous in t) -> 4 loads/thread
#pragma unroll
    for (int s = 0; s < 4; s++) {
      int w = s * 16 + wgs;
      float4 v = *(const float4*)&x[xb + (size_t)(w0 + w) * T_ + t0 + tqs * 4];
      tile[tqs * 4 + 0][w] = v.x;
      tile[tqs * 4 + 1][w] = v.y;
      tile[tqs * 4 + 2][w] = v.z;
      tile[tqs * 4 + 3][w] = v.w;
    }
    __syncthreads();
    // compute: thread owns cols wl4..wl4+3 of row t -> ushort4 stores
#pragma unroll
    for (int s = 0; s < 4; s++) {
      int t = s * 16 + tg;
      float v0 = tile[t][wl4 + 0], v1 = tile[t][wl4 + 1];
      float v2 = tile[t][wl4 + 2], v3 = tile[t][wl4 + 3];
      ushort4 hv, lv;
      hv.x = f2bf_hw(v0); lv.x = f2bf_hw(v0 - bf2f(hv.x));
      hv.y = f2bf_hw(v1); lv.y = f2bf_hw(v1 - bf2f(hv.y));
      hv.z = f2bf_hw(v2); lv.z = f2bf_hw(v2 - bf2f(hv.z));
      hv.w = f2bf_hw(v3); lv.w = f2bf_hw(v3 - bf2f(hv.w));
      size_t row = (size_t)n * 1024 + t0 + t;
      *(ushort4*)&xhi[row * 512 + w0 + wl4] = hv;
      *(ushort4*)&xlo[row * 512 + w0 + wl4] = lv;
      gs += v0 + v1 + v2 + v3;
      float part = v0 * v0 + v1 * v1 + v2 * v2 + v3 * v3;
      gq += part;
      for (int off = 8; off; off >>= 1) part += __shfl_down(part, off, 16);
      if ((tid & 15) == 0) x2s[t] += part;
    }
    __syncthreads();
  }
  for (int off = 32; off; off >>= 1) { gs += __shfl_down(gs, off, 64); gq += __shfl_down(gq, off, 64); }
  if ((tid & 63) == 0) { rs[tid >> 6] = gs; rq[tid >> 6] = gq; }
  __syncthreads();
  if (tid == 0) {
    atomicAdd(&scal[0], rs[0] + rs[1] + rs[2] + rs[3]);
    atomicAdd(&scal[1], rq[0] + rq[1] + rq[2] + rq[3]);
  }
  if (tid < 64) x2[n * 1024 + t0 + tid] = x2s[tid];
}

// ---------------- MFMA argmin: 128x128 tile, BK=64, split-bf16 3-term ----------------
// K-loop FROZEN: round-7 structure + addressing, HW-validated conflict-free.
// Epilogue: parallel 256-thread merge (R15) — bit-identical output.
__global__ __launch_bounds__(256, 2) void vq_argmin_mfma(
    const ushort_t* __restrict__ xhi, const ushort_t* __restrict__ xlo,
    const ushort_t* __restrict__ khi, const ushort_t* __restrict__ klo,
    const float* __restrict__ x2, const float* __restrict__ k2,
    unsigned long long* __restrict__ pm1, float* __restrict__ pm2) {
  __shared__ __align__(16) char smem[65536];
  int tid = threadIdx.x;
  int bx = blockIdx.x & 127, by = blockIdx.x >> 7;
  int row0 = bx * 128, col0 = by * 128;
  int lane = tid & 63, wid = tid >> 6;
  int wm = wid >> 1, wn = wid & 1;
  int lr = lane & 15, quad = lane >> 4;

  const char* gb[4];
  gb[0] = (const char*)xhi + (size_t)row0 * 1024;
  gb[1] = (const char*)xlo + (size_t)row0 * 1024;
  gb[2] = (const char*)khi + (size_t)col0 * 1024;
  gb[3] = (const char*)klo + (size_t)col0 * 1024;
  uint32_t goff[4], loff[4];
#pragma unroll
  for (int it = 0; it < 4; it++) {
    int cid = it * 256 + tid;
    int row = cid >> 3;
    int cc = (cid & 7) ^ (row & 7);
    goff[it] = row * 1024 + cc * 16;
    loff[it] = cid * 16;
  }
  uint32_t aoff[4], boff[4];
#pragma unroll
  for (int i = 0; i < 4; i++) {
    int ra = wm * 64 + i * 16 + lr;
    aoff[i] = ra * 128 + ((quad ^ (ra & 7)) * 16);
    int rb = wn * 64 + i * 16 + lr;
    boff[i] = rb * 128 + ((quad ^ (rb & 7)) * 16);
  }
  f32x4 acc[4][4] = {};

  for (int kt = 0; kt < 8; kt++) {
    uint32_t kofs = (uint32_t)kt * 128;
#pragma unroll
    for (int tl = 0; tl < 4; tl++)
#pragma unroll
      for (int it = 0; it < 4; it++)
        gload_lds16(gb[tl] + goff[it] + kofs, &smem[tl * 16384 + loff[it]]);
    __syncthreads();
#pragma unroll
    for (int kk = 0; kk < 2; kk++) {
      uint32_t kx = (uint32_t)kk << 6;
      short8 ah[4], al[4], bh[4], bl[4];
#pragma unroll
      for (int i = 0; i < 4; i++) {
        ah[i] = *(const short8*)&smem[(aoff[i] ^ kx)];
        al[i] = *(const short8*)&smem[16384 + (aoff[i] ^ kx)];
        bh[i] = *(const short8*)&smem[32768 + (boff[i] ^ kx)];
        bl[i] = *(const short8*)&smem[49152 + (boff[i] ^ kx)];
      }
#pragma unroll
      for (int i = 0; i < 4; i++)
#pragma unroll
        for (int j = 0; j < 4; j++) {
          acc[i][j] = __builtin_amdgcn_mfma_f32_16x16x32_bf16(ah[i], bh[j], acc[i][j], 0, 0, 0);
          acc[i][j] = __builtin_amdgcn_mfma_f32_16x16x32_bf16(ah[i], bl[j], acc[i][j], 0, 0, 0);
          acc[i][j] = __builtin_amdgcn_mfma_f32_16x16x32_bf16(al[i], bh[j], acc[i][j], 0, 0, 0);
        }
    }
    __syncthreads();
  }

  // epilogue: per-row top-2 into LDS [128][33] (padded), then PARALLEL 32-slot merge
  unsigned long long* L1 = (unsigned long long*)smem;   // [128][33] u64, 33792 B
  float* L2f = (float*)&smem[33792];                    // [128][33] f32, 16896 B
  unsigned long long* P1 = (unsigned long long*)&smem[50688];  // [128] u64, 1024 B
  float* P2 = (float*)&smem[51712];                            // [128] f32,  512 B
  float k2c[4];
#pragma unroll
  for (int j = 0; j < 4; j++) k2c[j] = k2[col0 + wn * 64 + j * 16 + lr];
#pragma unroll
  for (int i = 0; i < 4; i++) {
#pragma unroll
    for (int r = 0; r < 4; r++) {
      int row_l = wm * 64 + i * 16 + quad * 4 + r;
      float x2r = x2[row0 + row_l];
      float m1 = 3.4e38f, m2 = 3.4e38f; int mi = 0;
#pragma unroll
      for (int j = 0; j < 4; j++) {
        float d = (x2r - 2.0f * acc[i][j][r]) + k2c[j];
        int kg = col0 + wn * 64 + j * 16 + lr;
        if (d < m1) { m2 = m1; m1 = d; mi = kg; } else m2 = fminf(m2, d);
      }
      L1[row_l * 33 + wn * 16 + lr] =
          (((unsigned long long)__float_as_uint(m1)) << 32) | (unsigned)mi;
      L2f[row_l * 33 + wn * 16 + lr] = m2;
    }
  }
  __syncthreads();
  {
    int row = tid & 127;
    int half = tid >> 7;               // 0: slots 0-15, 1: slots 16-31
    int base = row * 33 + half * 16;
    unsigned long long b1 = L1[base];
    float b2 = L2f[base];
    for (int c = 1; c < 16; c++) {
      unsigned long long v = L1[base + c];
      float vf = L2f[base + c];
      if (v < b1) { b2 = fminf(b2, __uint_as_float((unsigned)(b1 >> 32))); b1 = v; }
      else b2 = fminf(b2, __uint_as_float((unsigned)(v >> 32)));
      b2 = fminf(b2, vf);
    }
    if (half) { P1[row] = b1; P2[row] = b2; }
    __syncthreads();
    if (!half) {
      unsigned long long o1 = P1[row];
      float o2 = P2[row];
      if (o1 < b1) { b2 = fminf(b2, __uint_as_float((unsigned)(b1 >> 32))); b1 = o1; }
      else b2 = fminf(b2, __uint_as_float((unsigned)(o1 >> 32)));
      b2 = fminf(b2, o2);
      pm1[(size_t)by * NT_ + row0 + row] = b1;
      pm2[(size_t)by * NT_ + row0 + row] = b2;
    }
  }
}

// ---------------- merge 16 col-blocks -> packed + compacted near-tie list ----------------
__global__ void vq_merge(const unsigned long long* __restrict__ pm1,
                         const float* __restrict__ pm2,
                         unsigned long long* __restrict__ packed,
                         int* __restrict__ flist, int* __restrict__ nflag) {
  int r = blockIdx.x * 256 + threadIdx.x;
  unsigned long long b1 = pm1[r];
  float b2 = pm2[r];
  for (int c = 1; c < 16; c++) {
    unsigned long long v = pm1[(size_t)c * NT_ + r];
    float vf = pm2[(size_t)c * NT_ + r];
    if (v < b1) { b2 = fminf(b2, __uint_as_float((unsigned)(b1 >> 32))); b1 = v; }
    else b2 = fminf(b2, __uint_as_float((unsigned)(v >> 32)));
    b2 = fminf(b2, vf);
  }
  if ((b2 - __uint_as_float((unsigned)(b1 >> 32))) < 3e-4f) {
    packed[r] = 0xFFFFFFFFFFFFFFFFull;
    int pos = atomicAdd(nflag, 1);
    flist[pos] = r;
  } else {
    packed[r] = b1;
  }
}

// ---------------- gather flagged x rows to dense fp32 (coalesced writes) ----------------
__global__ void vq_gatherx(const float* __restrict__ x, const int* __restrict__ flist,
                           const int* __restrict__ nflag, float* __restrict__ xg) {
  int nf = *nflag; if (nf > XG_CAP) nf = XG_CAP;
  int total = nf * 512;
  for (int e = blockIdx.x * 256 + threadIdx.x; e < total; e += gridDim.x * 256) {
    int ii = e >> 9, c = e & 511;
    int r = flist[ii];
    xg[e] = x[(size_t)(r >> 10) * 524288 + (size_t)c * 1024 + (r & 1023)];
  }
}

// ---------------- fp32 exact repair: (8-row group) x (256-cluster chunk) ----------------
__global__ void vq_repair(const float* __restrict__ x, const float* __restrict__ k,
                          const float* __restrict__ xg,
                          const float* __restrict__ x2, const float* __restrict__ k2,
                          const int* __restrict__ flist, const int* __restrict__ nflag,
                          unsigned long long* __restrict__ packed) {
  __shared__ float xs[8][512];
  __shared__ unsigned long long part[8][4];
  int tid = threadIdx.x;
  int lane = tid & 63, wave = tid >> 6;
  int nf = *nflag;
  int ngrp = (nf + 7) >> 3;
  int nwork = ngrp * 8;
  for (int wi = blockIdx.x; wi < nwork; wi += gridDim.x) {
    int g = wi >> 3, c = wi & 7;
    int base = g * 8;
    for (int e = tid; e < 8 * 512; e += 256) {
      int rr = e >> 9, cc = e & 511;
      int ii = base + rr;
      float v = 0.f;
      if (ii < nf) {
        if (ii < XG_CAP) v = xg[ii * 512 + cc];
        else { int r = flist[ii]; v = x[(size_t)(r >> 10) * 524288 + (size_t)cc * 1024 + (r & 1023)]; }
      }
      xs[rr][cc] = v;
    }
    __syncthreads();
    int j = c * 256 + tid;
    const float4* kr = (const float4*)(k + (size_t)j * 512);
    float dot[8] = {0.f, 0.f, 0.f, 0.f, 0.f, 0.f, 0.f, 0.f};
    for (int w4 = 0; w4 < 128; w4++) {
      float4 kv = kr[w4];
#pragma unroll
      for (int rr = 0; rr < 8; rr++) {
        const float4 xv = *(const float4*)&xs[rr][w4 * 4];
        dot[rr] = fmaf(xv.x, kv.x, dot[rr]);
        dot[rr] = fmaf(xv.y, kv.y, dot[rr]);
        dot[rr] = fmaf(xv.z, kv.z, dot[rr]);
        dot[rr] = fmaf(xv.w, kv.w, dot[rr]);
      }
    }
    float k2j = k2[j];
#pragma unroll
    for (int rr = 0; rr < 8; rr++) {
      int ii = base + rr;
      unsigned long long pv = 0xFFFFFFFFFFFFFFFFull;
      if (ii < nf) {
        int r = flist[ii];
        float d = (x2[r] - 2.0f * dot[rr]) + k2j;
        pv = (((unsigned long long)__float_as_uint(d)) << 32) | (unsigned)j;
      }
      for (int off = 32; off; off >>= 1) {
        unsigned long long o = __shfl_down(pv, off, 64);
        if (o < pv) pv = o;
      }
      if (lane == 0) part[rr][wave] = pv;
    }
    __syncthreads();
    if (tid < 8) {
      int ii = base + tid;
      if (ii < nf) {
        unsigned long long m = part[tid][0];
        if (part[tid][1] < m) m = part[tid][1];
        if (part[tid][2] < m) m = part[tid][2];
        if (part[tid][3] < m) m = part[tid][3];
        atomicMin(&packed[flist[ii]], m);
      }
    }
    __syncthreads();
  }
}

// ---------------- x_l, counts, fit ----------------
__global__ void vq_cnt2(const unsigned long long* __restrict__ packed,
                        float* __restrict__ counts, float* __restrict__ scal,
                        float* __restrict__ out) {
  int tid = threadIdx.x;
  int r = blockIdx.x * 256 + tid;
  unsigned long long p = packed[r];
  unsigned idx = (unsigned)(p & 0xFFFFFFFFull);
  float md = __uint_as_float((unsigned)(p >> 32));
  out[O_XL + r] = (float)idx;
  atomicAdd(&counts[idx], 1.0f);
  float s = md;
  for (int off = 32; off; off >>= 1) s += __shfl_down(s, off, 64);
  __shared__ float rs[4];
  if ((tid & 63) == 0) rs[tid >> 6] = s;
  __syncthreads();
  if (tid == 0) atomicAdd(&scal[2], rs[0] + rs[1] + rs[2] + rs[3]);
}

// ---------------- exclusive scan of counts -> offsets (parallel wave scan) ----------------
__global__ void vq_scan(const float* __restrict__ counts, int* __restrict__ offs) {
  __shared__ int wsum[4];
  int t = threadIdx.x;
  int loc[8];
  int s = 0;
#pragma unroll
  for (int c = 0; c < 8; c++) { loc[c] = (int)counts[t * 8 + c]; s += loc[c]; }
  int orig = s;
  int lane = t & 63, wave = t >> 6;
#pragma unroll
  for (int off = 1; off < 64; off <<= 1) {
    int v = __shfl_up(s, off, 64);
    if (lane >= off) s += v;
  }
  if (lane == 63) wsum[wave] = s;
  __syncthreads();
  int add = 0;
  for (int w = 0; w < 4; w++) if (w < wave) add += wsum[w];
  int excl = s + add - orig;
#pragma unroll
  for (int c = 0; c < 8; c++) {
    offs[t * 8 + c] = excl;
    excl += loc[c];
  }
  if (t == 255) offs[2048] = excl;
}

// ---------------- fused: CSR fill (blocks 0..63) + x_d gather/store (blocks 64..1087) ----------------
__global__ void vq_fill_xd(const unsigned long long* __restrict__ packed,
                           const int* __restrict__ offs, int* __restrict__ cursor,
                           int* __restrict__ rowl, const float* __restrict__ k,
                           float* __restrict__ out) {
  __shared__ int lrow[64];
  int tid = threadIdx.x;
  if (blockIdx.x < 64) {
    int r = blockIdx.x * 256 + tid;
    int idx = (int)(packed[r] & 0xFFFFFFFFull);
    int pos = atomicAdd(&cursor[idx], 1);
    rowl[offs[idx] + pos] = r;
    return;
  }
  int bid = blockIdx.x - 64;
  int tb = bid >> 2, wq = bid & 3;        // tb: 0..255 (64-row t-blocks), wq: 128-w quarter
  int row0 = tb * 64;
  int n = row0 >> 10, t0 = row0 & 1023;
  if (tid < 64) lrow[tid] = (int)(packed[row0 + tid] & 0xFFFFFFFFull);
  __syncthreads();
  int tq = (tid & 15) * 4;                // t offset within 64 (quad)
  int wl = tid >> 4;                      // 0..15
  const float* k0 = k + (size_t)lrow[tq + 0] * 512;
  const float* k1 = k + (size_t)lrow[tq + 1] * 512;
  const float* k2r = k + (size_t)lrow[tq + 2] * 512;
  const float* k3 = k + (size_t)lrow[tq + 3] * 512;
  float* xd = out + O_XD + (size_t)n * 524288 + t0 + tq;
#pragma unroll
  for (int it = 0; it < 8; it++) {
    int w = wq * 128 + it * 16 + wl;
    float4 v;
    v.x = k0[w]; v.y = k1[w]; v.z = k2r[w]; v.w = k3[w];
    *(float4*)&xd[(size_t)w * 1024] = v;
  }
}

// ---------------- codebook EMA update via CSR gather (8B loads, row-parity split) ----------------
__global__ void vq_knew_csr(const ushort_t* __restrict__ xhi, const ushort_t* __restrict__ xlo,
                            const float* __restrict__ k, const float* __restrict__ ksum_in,
                            const float* __restrict__ kelem_in, const int* __restrict__ offs,
                            const int* __restrict__ rowl, const int* __restrict__ krand,
                            float* __restrict__ out, float* __restrict__ scal) {
  __shared__ float4 sb[128];
  __shared__ float r4[4];
  int j = blockIdx.x, tid = threadIdx.x;
  int o0 = offs[j], o1 = offs[j + 1];
  int c = tid & 127;                      // col group: owns w0..w0+3
  int g = tid >> 7;                       // row parity
  int w0 = c * 4;
  float s0 = 0.f, s1 = 0.f, s2 = 0.f, s3 = 0.f;
  for (int p = o0 + g; p < o1; p += 2) {
    int r = rowl[p];
    uint2 ha = *(const uint2*)&xhi[(size_t)r * 512 + w0];
    uint2 la = *(const uint2*)&xlo[(size_t)r * 512 + w0];
    s0 += bf2f((ushort_t)ha.x) + bf2f((ushort_t)la.x);
    s1 += bf2f((ushort_t)(ha.x >> 16)) + bf2f((ushort_t)(la.x >> 16));
    s2 += bf2f((ushort_t)ha.y) + bf2f((ushort_t)la.y);
    s3 += bf2f((ushort_t)(ha.y >> 16)) + bf2f((ushort_t)(la.y >> 16));
  }
  if (g) { sb[c].x = s0; sb[c].y = s1; sb[c].z = s2; sb[c].w = s3; }
  __syncthreads();
  float cnt = (float)(o1 - o0);
  float ken = 0.99f * kelem_in[j] + 0.01f * cnt;
  bool use = (ken >= 1.0f);
  int ir = krand[j] & 16383;
  float dd = 0.f;
  if (!g) {
    float4 ps = sb[c];
    s0 += ps.x; s1 += ps.y; s2 += ps.z; s3 += ps.w;
    float4 ks = *(const float4*)&ksum_in[(size_t)j * 512 + w0];
    float4 kc = *(const float4*)&k[(size_t)j * 512 + w0];
    float ksn0 = 0.99f * ks.x + 0.01f * s0;
    float ksn1 = 0.99f * ks.y + 0.01f * s1;
    float ksn2 = 0.99f * ks.z + 0.01f * s2;
    float ksn3 = 0.99f * ks.w + 0.01f * s3;
    size_t ob = (size_t)j * 512 + w0;
    out[O_KSN + ob + 0] = ksn0;           // O_KSN/O_KNEW odd float offsets: scalar stores
    out[O_KSN + ob + 1] = ksn1;
    out[O_KSN + ob + 2] = ksn2;
    out[O_KSN + ob + 3] = ksn3;
    float kn0, kn1, kn2, kn3;
    if (use) {
      float inv = 1.0f / ken;
      kn0 = ksn0 * inv; kn1 = ksn1 * inv; kn2 = ksn2 * inv; kn3 = ksn3 * inv;
    } else {
      uint2 hr = *(const uint2*)&xhi[(size_t)ir * 512 + w0];
      uint2 lr = *(const uint2*)&xlo[(size_t)ir * 512 + w0];
      kn0 = bf2f((ushort_t)hr.x) + bf2f((ushort_t)lr.x);
      kn1 = bf2f((ushort_t)(hr.x >> 16)) + bf2f((ushort_t)(lr.x >> 16));
      kn2 = bf2f((ushort_t)hr.y) + bf2f((ushort_t)lr.y);
      kn3 = bf2f((ushort_t)(hr.y >> 16)) + bf2f((ushort_t)(lr.y >> 16));
    }
    out[O_KNEW + ob + 0] = kn0;
    out[O_KNEW + ob + 1] = kn1;
    out[O_KNEW + ob + 2] = kn2;
    out[O_KNEW + ob + 3] = kn3;
    float d0 = kn0 - kc.x, d1 = kn1 - kc.y, d2 = kn2 - kc.z, d3 = kn3 - kc.w;
    dd = d0 * d0 + d1 * d1 + d2 * d2 + d3 * d3;
  }
  for (int off = 32; off; off >>= 1) dd += __shfl_down(dd, off, 64);
  if ((tid & 63) == 0) r4[tid >> 6] = dd;
  __syncthreads();
  if (tid == 0) {
    atomicAdd(&scal[3], r4[0] + r4[1] + r4[2] + r4[3]);
    out[O_KEN + j] = ken;
  }
}

// ---------------- scalars ----------------
__global__ void vq_fin(const float* __restrict__ counts, const float* __restrict__ scal,
                       float* __restrict__ out) {
  int tid = threadIdx.x;
  float e = 0.f;
  for (int j = tid; j < K_; j += 256) {
    float p = counts[j] * (1.0f / 16384.0f);
    e -= p * logf(p + 1e-8f);
  }
  for (int off = 32; off; off >>= 1) e += __shfl_down(e, off, 64);
  __shared__ float r[4];
  if ((tid & 63) == 0) r[tid >> 6] = e;
  __syncthreads();
  if (tid == 0) {
    float ent = r[0] + r[1] + r[2] + r[3];
    float sum = scal[0], sumsq = scal[1], fits = scal[2], d2 = scal[3];
    const float S = 8388608.f;
    out[O_SC + 0] = fits / S;
    out[O_SC + 1] = fits / 16384.f;
    out[O_SC + 2] = sqrtf((sumsq - sum * sum / S) / S);
    out[O_SC + 3] = ent;
    out[O_SC + 4] = sqrtf(d2 / 1048576.f);
  }
}

extern "C" void kernel_launch(void* const* d_in, const int* in_sizes, int n_in,
                              void* d_out, int out_size, void* d_ws, size_t ws_size,
                              hipStream_t stream) {
  (void)in_sizes; (void)n_in; (void)out_size; (void)ws_size;
  const float* x        = (const float*)d_in[0];
  const float* k        = (const float*)d_in[1];
  const float* ksum_in  = (const float*)d_in[2];
  const float* kelem_in = (const float*)d_in[3];
  float* out = (float*)d_out;
  uint8_t* ws = (uint8_t*)d_ws;

  ushort_t* xhi = (ushort_t*)(ws + OFF_XHI);
  ushort_t* xlo = (ushort_t*)(ws + OFF_XLO);
  ushort_t* khi = (ushort_t*)(ws + OFF_KHI);
  ushort_t* klo = (ushort_t*)(ws + OFF_KLO);
  unsigned long long* pm1 = (unsigned long long*)(ws + OFF_PM1);
  float*    pm2    = (float*)(ws + OFF_PM2);
  float*    xg     = (float*)(ws + OFF_XG);
  unsigned long long* packed = (unsigned long long*)(ws + OFF_PACKED);
  int*      flist  = (int*)(ws + OFF_FLIST);
  float*    x2v    = (float*)(ws + OFF_X2);
  float*    k2v    = (float*)(ws + OFF_K2);
  float*    scal   = (float*)(ws + OFF_SCAL);
  int*      nflag  = (int*)(ws + OFF_SCAL + 32);
  float*    counts = (float*)(ws + OFF_COUNTS);
  int*      cursor = (int*)(ws + OFF_CURSOR);
  int*      offs   = (int*)(ws + OFF_OFFS);
  int*      rowl   = (int*)(ws + OFF_ROWL);
  int*      krand  = (int*)(ws + OFF_KRAND);

  if (!h_krand_ready) { compute_krand_host(); h_krand_ready = true; }

  // device-side memset for zeros (fast graph node) + small 8KB krand upload
  hipMemsetAsync(ws + OFF_SCAL, 0, ZERO_LEN, stream);
  hipMemcpyAsync(krand, h_krand, sizeof(h_krand), hipMemcpyHostToDevice, stream);

  vq_prep<<<512, 256, 0, stream>>>(x, k, xhi, xlo, x2v, scal, khi, klo, k2v);
  vq_argmin_mfma<<<2048, 256, 0, stream>>>(xhi, xlo, khi, klo, x2v, k2v, pm1, pm2);
  vq_merge<<<64, 256, 0, stream>>>(pm1, pm2, packed, flist, nflag);
  vq_gatherx<<<256, 256, 0, stream>>>(x, flist, nflag, xg);
  vq_repair<<<512, 256, 0, stream>>>(x, k, xg, x2v, k2v, flist, nflag, packed);
  vq_cnt2<<<64, 256, 0, stream>>>(packed, counts, scal, out);
  vq_scan<<<1, 256, 0, stream>>>(counts, offs);
  vq_fill_xd<<<1088, 256, 0, stream>>>(packed, offs, cursor, rowl, k, out);
  vq_knew_csr<<<2048, 256, 0, stream>>>(xhi, xlo, k, ksum_in, kelem_in, offs, rowl, krand, out, scal);
  vq_fin<<<1, 256, 0, stream>>>(counts, scal, out);
}